// Round 6
// baseline (51.865 us; speedup 1.0000x reference)
//
#include <hip/hip_runtime.h>

// LIF forward: x [T=32, B=64, N=16384] f32 -> spikes (0/1) f32, same shape.
// mem_t = mem_{t-1}*0.25 + x_t ; s_t = (mem_t > 1) ; reset mem on spike.
// Bit-exact vs numpy.
//
// R5 post-mortem: compiler re-interleaved the load/compute phases
// (VGPR=20 proves only ~4-8 xv values were live) -> load_{t+1}'s
// consumption still waited on store_t's write-ack via in-order vmcnt
// retirement -> one step per ~900cy HBM latency (matches measured
// 4.2 TB/s at 18 waves/CU x 512 B/step).
// Fix: sched_barrier(0) between phases pins the schedule. All 32 loads
// issue first (oldest in vmcnt queue); compute step t waits vmcnt(31)
// which is satisfiable with every store still outstanding -> stores
// never gate loads. VGPR ~44 still allows 8 waves/SIMD.

__global__ __launch_bounds__(256, 8) void lif_fwd_kernel(
    const float* __restrict__ x, float* __restrict__ out, int BN) {
    const size_t i = (size_t)blockIdx.x * 256 + threadIdx.x;

    // Phase 1: 32 back-to-back loads (8 KB/wave in flight).
    float xv[32];
    #pragma unroll
    for (int t = 0; t < 32; ++t)
        xv[t] = x[(size_t)t * BN + i];

    // Hard scheduling fence: nothing crosses. Keeps all loads grouped
    // ahead of every store so in-order vmcnt retirement never couples
    // a load's consumption to a store's ack.
    __builtin_amdgcn_sched_barrier(0);

    // Phase 2: sequential LIF chain + store stream.
    float mem = 0.f;
    #pragma unroll
    for (int t = 0; t < 32; ++t) {
        mem = mem * 0.25f + xv[t];
        const float s = (mem > 1.0f) ? 1.0f : 0.0f;
        mem = (s != 0.0f) ? 0.0f : mem;
        out[(size_t)t * BN + i] = s;
    }
}

extern "C" void kernel_launch(void* const* d_in, const int* in_sizes, int n_in,
                              void* d_out, int out_size, void* d_ws, size_t ws_size,
                              hipStream_t stream) {
    const float* x = (const float*)d_in[0];
    float* out = (float*)d_out;

    const int T = 32;
    const int total = in_sizes[0];        // 33,554,432
    const int BN = total / T;             // 1,048,576 (divisible by 256)

    const int block = 256;
    const int grid = BN / block;          // 4096

    lif_fwd_kernel<<<grid, block, 0, stream>>>(x, out, BN);
}

// Round 7
// 51.550 us; speedup vs baseline: 1.0061x; 1.0061x over previous
//
#include <hip/hip_runtime.h>

// LIF forward: x [T=32, B=64, N=16384] f32 -> spikes (0/1) f32, same shape.
// mem_t = mem_{t-1}*0.25 + x_t ; s_t = (mem_t > 1) ; reset mem on spike.
// Bit-exact vs numpy.
//
// R6 post-mortem: sched_barrier alone didn't stop IR-level load sinking
// (VGPR stayed 20 -> MLP~1/wave). Little's law check: 21 waves/CU x 256 B
// x 1 outstanding / 900cy = 14 GB/s/CU = measured 15. Latency-bound.
// Fix: per-value asm volatile("+v") keep-alives after the load loop force
// all 32 loads to materialize in VGPRs before phase 2 -- compiler cannot
// sink a load past an asm that reads its result. Load-phase waits are
// load-only (stores not yet issued -> no store-ack coupling). Phase 2 is
// wait-free compute + store stream.

__global__ __launch_bounds__(256, 8) void lif_fwd_kernel(
    const float* __restrict__ x, float* __restrict__ out, int BN) {
    const size_t i = (size_t)blockIdx.x * 256 + threadIdx.x;

    // Phase 1: 32 back-to-back loads (8 KB/wave in flight).
    float xv[32];
    #pragma unroll
    for (int t = 0; t < 32; ++t)
        xv[t] = x[(size_t)t * BN + i];

    // Force every xv[t] live in a VGPR here: loads cannot be sunk into
    // phase 2, so all 32 issue before any store.
    #pragma unroll
    for (int t = 0; t < 32; ++t)
        asm volatile("" : "+v"(xv[t]));

    __builtin_amdgcn_sched_barrier(0);

    // Phase 2: sequential LIF chain + store stream (no vmcnt waits).
    float mem = 0.f;
    #pragma unroll
    for (int t = 0; t < 32; ++t) {
        mem = mem * 0.25f + xv[t];
        const float s = (mem > 1.0f) ? 1.0f : 0.0f;
        mem = (s != 0.0f) ? 0.0f : mem;
        out[(size_t)t * BN + i] = s;
    }
}

extern "C" void kernel_launch(void* const* d_in, const int* in_sizes, int n_in,
                              void* d_out, int out_size, void* d_ws, size_t ws_size,
                              hipStream_t stream) {
    const float* x = (const float*)d_in[0];
    float* out = (float*)d_out;

    const int T = 32;
    const int total = in_sizes[0];        // 33,554,432
    const int BN = total / T;             // 1,048,576 (divisible by 256)

    const int block = 256;
    const int grid = BN / block;          // 4096

    lif_fwd_kernel<<<grid, block, 0, stream>>>(x, out, BN);
}